// Round 9
// baseline (68.648 us; speedup 1.0000x reference)
//
#include <hip/hip_runtime.h>
#include <hip/hip_fp16.h>
#include <float.h>

#define C_    512
#define H_    38
#define W_    50
#define HW_   (H_ * W_)       // 1900
#define NROIS 1024
#define PS    7
#define PRE   14              // PS*2
#define NCELL 49              // PS*PS
#define CQ    128             // channels per block (quarter)
#define NGP   (PRE * PRE)     // 196 gridpoints

typedef float vfloat4 __attribute__((ext_vector_type(4)));
typedef _Float16 h2 __attribute__((ext_vector_type(2)));

// ---------------------------------------------------------------------------
// Transpose + downconvert: bottom (C, H*W) f32 -> (H*W, C) fp16.
// ---------------------------------------------------------------------------
__global__ __launch_bounds__(256) void transpose_kernel(
    const float* __restrict__ in, _Float16* __restrict__ out) {
    __shared__ float tile[32][33];
    const int pix0 = blockIdx.x * 32;
    const int c0   = blockIdx.y * 32;
    const int tx = threadIdx.x & 31;
    const int ty = threadIdx.x >> 5;

    for (int i = ty; i < 32; i += 8) {
        int c = c0 + i, pix = pix0 + tx;
        tile[i][tx] = (pix < HW_) ? in[c * HW_ + pix] : 0.0f;
    }
    __syncthreads();
    for (int i = ty; i < 32; i += 8) {
        int pix = pix0 + i, c = c0 + tx;
        if (pix < HW_) out[pix * C_ + c] = (_Float16)tile[tx][i];
    }
}

// ---------------------------------------------------------------------------
// Main crop-and-maxpool kernel (transposed fp16 src: src[pix*512 + c]).
// grid = NROIS*4; block = 256 (4 waves). Block (n,cq): ROI n, channels
// [cq*128, cq*128+128). Lanes 0-31: cell's top 2 gridpoints; lanes 32-63:
// bottom 2. Lane loads 4 fp16 channels (8B) per corner. fp16 outtile in
// [cell][channel] layout (12.5 KB) -> 18.8 KB LDS total -> 8 blocks/CU.
// ---------------------------------------------------------------------------
__global__ __launch_bounds__(256, 8) void croppool_kernel(
    const _Float16* __restrict__ src, const float* __restrict__ rois,
    float* __restrict__ out) {

    const int n  = blockIdx.x >> 2;
    const int cq = blockIdx.x & 3;
    const int cbase = cq * CQ;
    const int tid = threadIdx.x;

    __shared__ _Float16 outtile[NCELL * CQ];  // [cell][c_local] (12544 B)
    __shared__ int4  offt[NGP];               // 4 corner offsets (half elements)
    __shared__ h2    wgtt[NGP][4];            // 4 corner weights, duplicated (16B/gp)

    // --- per-gridpoint tables (align_corners=True + zeros padding) ---
    if (tid < NGP) {
        const int gy = tid / PRE, gx = tid - PRE * gy;
        const float rx1 = rois[n * 5 + 1] * 0.0625f;
        const float ry1 = rois[n * 5 + 2] * 0.0625f;
        const float rx2 = rois[n * 5 + 3] * 0.0625f;
        const float ry2 = rois[n * 5 + 4] * 0.0625f;

        int xi0, xi1, yi0, yi1;
        float wx0, wx1, wy0, wy1;
        {   // x axis
            const float sz = (float)(W_ - 1);
            const float t0 = (rx2 - rx1) / sz, tc = (rx1 + rx2 - sz) / sz;
            const float base = -1.0f + (float)gx * (2.0f / 13.0f);
            const float coord = (t0 * base + tc + 1.0f) * 0.5f * sz;
            const float f = floorf(coord), a = coord - f;
            const int i0 = (int)f, i1 = i0 + 1;
            wx0 = (i0 >= 0 && i0 <= W_ - 1) ? (1.0f - a) : 0.0f;
            wx1 = (i1 >= 0 && i1 <= W_ - 1) ? a : 0.0f;
            xi0 = min(max(i0, 0), W_ - 1);
            xi1 = min(max(i1, 0), W_ - 1);
        }
        {   // y axis
            const float sz = (float)(H_ - 1);
            const float t0 = (ry2 - ry1) / sz, tc = (ry1 + ry2 - sz) / sz;
            const float base = -1.0f + (float)gy * (2.0f / 13.0f);
            const float coord = (t0 * base + tc + 1.0f) * 0.5f * sz;
            const float f = floorf(coord), a = coord - f;
            const int i0 = (int)f, i1 = i0 + 1;
            wy0 = (i0 >= 0 && i0 <= H_ - 1) ? (1.0f - a) : 0.0f;
            wy1 = (i1 >= 0 && i1 <= H_ - 1) ? a : 0.0f;
            yi0 = min(max(i0, 0), H_ - 1);
            yi1 = min(max(i1, 0), H_ - 1);
        }
        offt[tid] = make_int4((yi0 * W_ + xi0) * C_, (yi0 * W_ + xi1) * C_,
                              (yi1 * W_ + xi0) * C_, (yi1 * W_ + xi1) * C_);
        const _Float16 w0 = (_Float16)(wy0 * wx0);
        const _Float16 w1 = (_Float16)(wy0 * wx1);
        const _Float16 w2 = (_Float16)(wy1 * wx0);
        const _Float16 w3 = (_Float16)(wy1 * wx1);
        wgtt[tid][0] = (h2){w0, w0};
        wgtt[tid][1] = (h2){w1, w1};
        wgtt[tid][2] = (h2){w2, w2};
        wgtt[tid][3] = (h2){w3, w3};
    }
    __syncthreads();

    const int lane32 = tid & 31;         // channel group (4 ch each)
    const int half_  = (tid >> 5) & 1;   // gridpoint row within cell
    const int wave   = tid >> 6;
    const _Float16* srcc = src + cbase + 4 * lane32;
    unsigned int* ot32 = (unsigned int*)outtile;

    for (int cell = wave; cell < NCELL; cell += 4) {
        const int py = cell / PS, px = cell - PS * py;
        const int gp = (2 * py + half_) * PRE + 2 * px;

        const int4 oA = offt[gp], oB = offt[gp + 1];
        const uint4 wvA = *(const uint4*)&wgtt[gp][0];      // one b128
        const uint4 wvB = *(const uint4*)&wgtt[gp + 1][0];  // one b128
        const h2 wA0 = __builtin_bit_cast(h2, wvA.x), wA1 = __builtin_bit_cast(h2, wvA.y);
        const h2 wA2 = __builtin_bit_cast(h2, wvA.z), wA3 = __builtin_bit_cast(h2, wvA.w);
        const h2 wB0 = __builtin_bit_cast(h2, wvB.x), wB1 = __builtin_bit_cast(h2, wvB.y);
        const h2 wB2 = __builtin_bit_cast(h2, wvB.z), wB3 = __builtin_bit_cast(h2, wvB.w);

        const uint2 A0 = *(const uint2*)(srcc + oA.x);
        const uint2 A1 = *(const uint2*)(srcc + oA.y);
        const uint2 A2 = *(const uint2*)(srcc + oA.z);
        const uint2 A3 = *(const uint2*)(srcc + oA.w);
        const uint2 B0 = *(const uint2*)(srcc + oB.x);
        const uint2 B1 = *(const uint2*)(srcc + oB.y);
        const uint2 B2 = *(const uint2*)(srcc + oB.z);
        const uint2 B3 = *(const uint2*)(srcc + oB.w);

        h2 vAl = wA0 * __builtin_bit_cast(h2, A0.x)
               + wA1 * __builtin_bit_cast(h2, A1.x)
               + wA2 * __builtin_bit_cast(h2, A2.x)
               + wA3 * __builtin_bit_cast(h2, A3.x);
        h2 vAh = wA0 * __builtin_bit_cast(h2, A0.y)
               + wA1 * __builtin_bit_cast(h2, A1.y)
               + wA2 * __builtin_bit_cast(h2, A2.y)
               + wA3 * __builtin_bit_cast(h2, A3.y);
        h2 vBl = wB0 * __builtin_bit_cast(h2, B0.x)
               + wB1 * __builtin_bit_cast(h2, B1.x)
               + wB2 * __builtin_bit_cast(h2, B2.x)
               + wB3 * __builtin_bit_cast(h2, B3.x);
        h2 vBh = wB0 * __builtin_bit_cast(h2, B0.y)
               + wB1 * __builtin_bit_cast(h2, B1.y)
               + wB2 * __builtin_bit_cast(h2, B2.y)
               + wB3 * __builtin_bit_cast(h2, B3.y);

        h2 mlo = __builtin_elementwise_max(vAl, vBl);
        h2 mhi = __builtin_elementwise_max(vAh, vBh);

        // combine across the two halves (ry=0 vs ry=1)
        {
            int t = __shfl_xor(__builtin_bit_cast(int, mlo), 32, 64);
            mlo = __builtin_elementwise_max(mlo, __builtin_bit_cast(h2, t));
            t = __shfl_xor(__builtin_bit_cast(int, mhi), 32, 64);
            mhi = __builtin_elementwise_max(mhi, __builtin_bit_cast(h2, t));
        }

        // lane writes its 2 consecutive channels as one 4B LDS word
        const h2 sel = half_ ? mhi : mlo;
        ot32[cell * (CQ / 2) + 2 * lane32 + half_] = __builtin_bit_cast(unsigned int, sel);
    }
    __syncthreads();

    // --- flush: convert fp16 [cell][c] tile -> f32 out[n][cbase..][cell] ---
    float* dstb = out + (size_t)n * (C_ * NCELL) + cbase * NCELL;
    for (int g = tid; g < CQ * NCELL / 4; g += 256) {
        vfloat4 v;
        #pragma unroll
        for (int j = 0; j < 4; ++j) {
            const int f = 4 * g + j;
            const int c = f / NCELL, cell = f - NCELL * c;
            v[j] = (float)outtile[cell * CQ + c];
        }
        __builtin_nontemporal_store(v, (vfloat4*)(dstb + 4 * g));
    }
}

// ---------------------------------------------------------------------------
// Fallback (reads original (C,H*W) f32 layout directly) — only if d_ws tiny.
// ---------------------------------------------------------------------------
__global__ __launch_bounds__(256) void croppool_fallback(
    const float* __restrict__ src, const float* __restrict__ rois,
    float* __restrict__ out) {

    const int n  = blockIdx.x >> 2;
    const int cq = blockIdx.x & 3;
    const int cbase = cq * CQ;
    const int tid = threadIdx.x;

    __shared__ float outtile[CQ * NCELL];
    __shared__ int   xi0[PRE], xi1[PRE], yi0[PRE], yi1[PRE];
    __shared__ float xw0[PRE], xw1[PRE], yw0[PRE], yw1[PRE];

    if (tid < 2 * PRE) {
        const int  j   = tid % PRE;
        const bool isy = tid >= PRE;
        const float r1 = rois[n * 5 + (isy ? 2 : 1)] * 0.0625f;
        const float r2 = rois[n * 5 + (isy ? 4 : 3)] * 0.0625f;
        const float sz = isy ? (float)(H_ - 1) : (float)(W_ - 1);
        const int  szi = isy ? (H_ - 1) : (W_ - 1);
        const float t0 = (r2 - r1) / sz;
        const float tc = (r1 + r2 - sz) / sz;
        const float base = -1.0f + (float)j * (2.0f / 13.0f);
        const float coord = (t0 * base + tc + 1.0f) * 0.5f * sz;
        const float f = floorf(coord);
        const float a = coord - f;
        const int i0 = (int)f;
        const int i1 = i0 + 1;
        const float w0 = (i0 >= 0 && i0 <= szi) ? (1.0f - a) : 0.0f;
        const float w1 = (i1 >= 0 && i1 <= szi) ? a : 0.0f;
        const int i0c = min(max(i0, 0), szi);
        const int i1c = min(max(i1, 0), szi);
        if (isy) { yi0[j] = i0c; yi1[j] = i1c; yw0[j] = w0; yw1[j] = w1; }
        else     { xi0[j] = i0c; xi1[j] = i1c; xw0[j] = w0; xw1[j] = w1; }
    }
    __syncthreads();

    const int wave = tid >> 6;
    const int lane = tid & 63;
    const float* srcc = src + (size_t)(cbase + lane) * HW_;

    for (int cell = wave; cell < NCELL; cell += 4) {
        const int py = cell / PS, px = cell % PS;
        float m0 = -FLT_MAX, m1 = -FLT_MAX;
        for (int ry = 0; ry < 2; ++ry) {
            const int gy = 2 * py + ry;
            for (int rx = 0; rx < 2; ++rx) {
                const int gx = 2 * px + rx;
                const int i00 = yi0[gy] * W_ + xi0[gx], i01 = yi0[gy] * W_ + xi1[gx];
                const int i10 = yi1[gy] * W_ + xi0[gx], i11 = yi1[gy] * W_ + xi1[gx];
                const float v0 = yw0[gy] * (xw0[gx] * srcc[i00] + xw1[gx] * srcc[i01])
                               + yw1[gy] * (xw0[gx] * srcc[i10] + xw1[gx] * srcc[i11]);
                const float v1 = yw0[gy] * (xw0[gx] * srcc[64 * HW_ + i00] + xw1[gx] * srcc[64 * HW_ + i01])
                               + yw1[gy] * (xw0[gx] * srcc[64 * HW_ + i10] + xw1[gx] * srcc[64 * HW_ + i11]);
                m0 = fmaxf(m0, v0);
                m1 = fmaxf(m1, v1);
            }
        }
        outtile[lane * NCELL + cell]        = m0;
        outtile[(lane + 64) * NCELL + cell] = m1;
    }
    __syncthreads();

    const vfloat4* lsrc = (const vfloat4*)outtile;
    vfloat4* dst = (vfloat4*)out + (size_t)n * (C_ * NCELL / 4) + cq * (CQ * NCELL / 4);
    for (int i = tid; i < CQ * NCELL / 4; i += 256) {
        __builtin_nontemporal_store(lsrc[i], &dst[i]);
    }
}

extern "C" void kernel_launch(void* const* d_in, const int* in_sizes, int n_in,
                              void* d_out, int out_size, void* d_ws, size_t ws_size,
                              hipStream_t stream) {
    const float* bottom = (const float*)d_in[0];   // (1, 512, 38, 50)
    const float* rois   = (const float*)d_in[1];   // (1024, 5)
    float* out = (float*)d_out;                    // (1024, 512, 7, 7)

    const size_t trans_bytes = (size_t)HW_ * C_ * sizeof(_Float16);
    if (ws_size >= trans_bytes) {
        _Float16* trans = (_Float16*)d_ws;
        dim3 tgrid((HW_ + 31) / 32, C_ / 32);
        transpose_kernel<<<tgrid, 256, 0, stream>>>(bottom, trans);
        croppool_kernel<<<NROIS * 4, 256, 0, stream>>>(trans, rois, out);
    } else {
        croppool_fallback<<<NROIS * 4, 256, 0, stream>>>(bottom, rois, out);
    }
}

// Round 10
// 46.559 us; speedup vs baseline: 1.4744x; 1.4744x over previous
//
#include <hip/hip_runtime.h>
#include <hip/hip_fp16.h>
#include <float.h>

#define C_    512
#define H_    38
#define W_    50
#define HW_   (H_ * W_)       // 1900
#define NROIS 1024
#define PS    7
#define PRE   14              // PS*2
#define NCELL 49              // PS*PS
#define CQ    128             // channels per block (quarter)
#define NGP   (PRE * PRE)     // 196 gridpoints

typedef float vfloat4 __attribute__((ext_vector_type(4)));
typedef _Float16 h2 __attribute__((ext_vector_type(2)));

__device__ inline h2 bch2(int v)   { return __builtin_bit_cast(h2, v); }
__device__ inline h2 bch2u(unsigned v) { return __builtin_bit_cast(h2, v); }
__device__ inline int bcint(h2 v)  { return __builtin_bit_cast(int, v); }

// ---------------------------------------------------------------------------
// Transpose + downconvert: bottom (C, H*W) f32 -> (H*W, C) fp16.
// ---------------------------------------------------------------------------
__global__ __launch_bounds__(256) void transpose_kernel(
    const float* __restrict__ in, _Float16* __restrict__ out) {
    __shared__ float tile[32][33];
    const int pix0 = blockIdx.x * 32;
    const int c0   = blockIdx.y * 32;
    const int tx = threadIdx.x & 31;
    const int ty = threadIdx.x >> 5;

    for (int i = ty; i < 32; i += 8) {
        int c = c0 + i, pix = pix0 + tx;
        tile[i][tx] = (pix < HW_) ? in[c * HW_ + pix] : 0.0f;
    }
    __syncthreads();
    for (int i = ty; i < 32; i += 8) {
        int pix = pix0 + i, c = c0 + tx;
        if (pix < HW_) out[pix * C_ + c] = (_Float16)tile[tx][i];
    }
}

// ---------------------------------------------------------------------------
// Main crop-and-maxpool kernel (transposed fp16 src: src[pix*512 + c]).
// grid = NROIS*4; block = 256 (4 waves). Block (n,cq): ROI n, channels
// [cq*128, cq*128+128).
// Per cell: the wave's 4 x 16-lane groups each own one of the cell's 4
// gridpoints (q = lane>>4: qy=q>>1, qx=q&1); lane loads 16B = 8 fp16
// channels per corner -> 4 coalesced 1KB wave-loads per cell. Max over
// gridpoints via shfl_xor(16)+shfl_xor(32). fp16 outtile [c][cell]
// (stride 49 halfwords -> conflict-free), 18.8 KB LDS -> 8 blocks/CU.
// ---------------------------------------------------------------------------
__global__ __launch_bounds__(256, 8) void croppool_kernel(
    const _Float16* __restrict__ src, const float* __restrict__ rois,
    float* __restrict__ out) {

    const int n  = blockIdx.x >> 2;
    const int cq = blockIdx.x & 3;
    const int cbase = cq * CQ;
    const int tid = threadIdx.x;

    __shared__ _Float16 outtile[CQ * NCELL];  // [c][cell], 12544 B
    __shared__ int4  offt[NGP];               // 4 corner offsets (half elems)
    __shared__ uint4 wgtt[NGP];               // 4 corner weights as packed h2

    // --- per-gridpoint tables (align_corners=True + zeros padding) ---
    if (tid < NGP) {
        const int gy = tid / PRE, gx = tid - PRE * gy;
        const float rx1 = rois[n * 5 + 1] * 0.0625f;
        const float ry1 = rois[n * 5 + 2] * 0.0625f;
        const float rx2 = rois[n * 5 + 3] * 0.0625f;
        const float ry2 = rois[n * 5 + 4] * 0.0625f;

        int xi0, xi1, yi0, yi1;
        float wx0, wx1, wy0, wy1;
        {   // x axis
            const float sz = (float)(W_ - 1);
            const float t0 = (rx2 - rx1) / sz, tc = (rx1 + rx2 - sz) / sz;
            const float base = -1.0f + (float)gx * (2.0f / 13.0f);
            const float coord = (t0 * base + tc + 1.0f) * 0.5f * sz;
            const float f = floorf(coord), a = coord - f;
            const int i0 = (int)f, i1 = i0 + 1;
            wx0 = (i0 >= 0 && i0 <= W_ - 1) ? (1.0f - a) : 0.0f;
            wx1 = (i1 >= 0 && i1 <= W_ - 1) ? a : 0.0f;
            xi0 = min(max(i0, 0), W_ - 1);
            xi1 = min(max(i1, 0), W_ - 1);
        }
        {   // y axis
            const float sz = (float)(H_ - 1);
            const float t0 = (ry2 - ry1) / sz, tc = (ry1 + ry2 - sz) / sz;
            const float base = -1.0f + (float)gy * (2.0f / 13.0f);
            const float coord = (t0 * base + tc + 1.0f) * 0.5f * sz;
            const float f = floorf(coord), a = coord - f;
            const int i0 = (int)f, i1 = i0 + 1;
            wy0 = (i0 >= 0 && i0 <= H_ - 1) ? (1.0f - a) : 0.0f;
            wy1 = (i1 >= 0 && i1 <= H_ - 1) ? a : 0.0f;
            yi0 = min(max(i0, 0), H_ - 1);
            yi1 = min(max(i1, 0), H_ - 1);
        }
        offt[tid] = make_int4((yi0 * W_ + xi0) * C_, (yi0 * W_ + xi1) * C_,
                              (yi1 * W_ + xi0) * C_, (yi1 * W_ + xi1) * C_);
        const _Float16 w0 = (_Float16)(wy0 * wx0);
        const _Float16 w1 = (_Float16)(wy0 * wx1);
        const _Float16 w2 = (_Float16)(wy1 * wx0);
        const _Float16 w3 = (_Float16)(wy1 * wx1);
        uint4 wv;
        wv.x = __builtin_bit_cast(unsigned, (h2){w0, w0});
        wv.y = __builtin_bit_cast(unsigned, (h2){w1, w1});
        wv.z = __builtin_bit_cast(unsigned, (h2){w2, w2});
        wv.w = __builtin_bit_cast(unsigned, (h2){w3, w3});
        wgtt[tid] = wv;
    }
    __syncthreads();

    const int m    = tid & 15;          // channel octet (8 ch each)
    const int q    = (tid >> 4) & 3;    // gridpoint quarter of the cell
    const int wave = tid >> 6;
    const _Float16* srcc = src + cbase + 8 * m;

    for (int cell = wave; cell < NCELL; cell += 4) {
        const int py = cell / PS, px = cell - PS * py;
        const int gp = (2 * py + (q >> 1)) * PRE + 2 * px + (q & 1);

        const int4  o  = offt[gp];
        const uint4 wv = wgtt[gp];
        const h2 w0 = bch2u(wv.x), w1 = bch2u(wv.y);
        const h2 w2 = bch2u(wv.z), w3 = bch2u(wv.w);

        const uint4 v0 = *(const uint4*)(srcc + o.x);
        const uint4 v1 = *(const uint4*)(srcc + o.y);
        const uint4 v2 = *(const uint4*)(srcc + o.z);
        const uint4 v3 = *(const uint4*)(srcc + o.w);

        h2 a0 = w0 * bch2u(v0.x) + w1 * bch2u(v1.x) + w2 * bch2u(v2.x) + w3 * bch2u(v3.x);
        h2 a1 = w0 * bch2u(v0.y) + w1 * bch2u(v1.y) + w2 * bch2u(v2.y) + w3 * bch2u(v3.y);
        h2 a2 = w0 * bch2u(v0.z) + w1 * bch2u(v1.z) + w2 * bch2u(v2.z) + w3 * bch2u(v3.z);
        h2 a3 = w0 * bch2u(v0.w) + w1 * bch2u(v1.w) + w2 * bch2u(v2.w) + w3 * bch2u(v3.w);

        // max over the 4 gridpoints (quarters)
        #pragma unroll
        for (int s = 16; s <= 32; s <<= 1) {
            a0 = __builtin_elementwise_max(a0, bch2(__shfl_xor(bcint(a0), s, 64)));
            a1 = __builtin_elementwise_max(a1, bch2(__shfl_xor(bcint(a1), s, 64)));
            a2 = __builtin_elementwise_max(a2, bch2(__shfl_xor(bcint(a2), s, 64)));
            a3 = __builtin_elementwise_max(a3, bch2(__shfl_xor(bcint(a3), s, 64)));
        }

        // lane's quarter selects its 2 channels; write 2 x u16 at stride 49
        const h2 sel = (q == 0) ? a0 : (q == 1) ? a1 : (q == 2) ? a2 : a3;
        const int c0 = 8 * m + 2 * q;
        outtile[c0 * NCELL + cell]       = sel.x;
        outtile[(c0 + 1) * NCELL + cell] = sel.y;
    }
    __syncthreads();

    // --- flush: contiguous b128 LDS reads, fp16->f32, contiguous nt stores ---
    float* dstb = out + (size_t)n * (C_ * NCELL) + cbase * NCELL;
    const uint4* lsrc = (const uint4*)outtile;
    for (int g = tid; g < CQ * NCELL / 8; g += 256) {
        const uint4 p = lsrc[g];
        vfloat4 lo, hi;
        h2 h;
        h = bch2u(p.x); lo[0] = (float)h.x; lo[1] = (float)h.y;
        h = bch2u(p.y); lo[2] = (float)h.x; lo[3] = (float)h.y;
        h = bch2u(p.z); hi[0] = (float)h.x; hi[1] = (float)h.y;
        h = bch2u(p.w); hi[2] = (float)h.x; hi[3] = (float)h.y;
        __builtin_nontemporal_store(lo, (vfloat4*)(dstb + 8 * g));
        __builtin_nontemporal_store(hi, (vfloat4*)(dstb + 8 * g + 4));
    }
}

// ---------------------------------------------------------------------------
// Fallback (reads original (C,H*W) f32 layout directly) — only if d_ws tiny.
// ---------------------------------------------------------------------------
__global__ __launch_bounds__(256) void croppool_fallback(
    const float* __restrict__ src, const float* __restrict__ rois,
    float* __restrict__ out) {

    const int n  = blockIdx.x >> 2;
    const int cq = blockIdx.x & 3;
    const int cbase = cq * CQ;
    const int tid = threadIdx.x;

    __shared__ float outtile[CQ * NCELL];
    __shared__ int   xi0[PRE], xi1[PRE], yi0[PRE], yi1[PRE];
    __shared__ float xw0[PRE], xw1[PRE], yw0[PRE], yw1[PRE];

    if (tid < 2 * PRE) {
        const int  j   = tid % PRE;
        const bool isy = tid >= PRE;
        const float r1 = rois[n * 5 + (isy ? 2 : 1)] * 0.0625f;
        const float r2 = rois[n * 5 + (isy ? 4 : 3)] * 0.0625f;
        const float sz = isy ? (float)(H_ - 1) : (float)(W_ - 1);
        const int  szi = isy ? (H_ - 1) : (W_ - 1);
        const float t0 = (r2 - r1) / sz;
        const float tc = (r1 + r2 - sz) / sz;
        const float base = -1.0f + (float)j * (2.0f / 13.0f);
        const float coord = (t0 * base + tc + 1.0f) * 0.5f * sz;
        const float f = floorf(coord);
        const float a = coord - f;
        const int i0 = (int)f;
        const int i1 = i0 + 1;
        const float w0 = (i0 >= 0 && i0 <= szi) ? (1.0f - a) : 0.0f;
        const float w1 = (i1 >= 0 && i1 <= szi) ? a : 0.0f;
        const int i0c = min(max(i0, 0), szi);
        const int i1c = min(max(i1, 0), szi);
        if (isy) { yi0[j] = i0c; yi1[j] = i1c; yw0[j] = w0; yw1[j] = w1; }
        else     { xi0[j] = i0c; xi1[j] = i1c; xw0[j] = w0; xw1[j] = w1; }
    }
    __syncthreads();

    const int wave = tid >> 6;
    const int lane = tid & 63;
    const float* srcc = src + (size_t)(cbase + lane) * HW_;

    for (int cell = wave; cell < NCELL; cell += 4) {
        const int py = cell / PS, px = cell % PS;
        float m0 = -FLT_MAX, m1 = -FLT_MAX;
        for (int ry = 0; ry < 2; ++ry) {
            const int gy = 2 * py + ry;
            for (int rx = 0; rx < 2; ++rx) {
                const int gx = 2 * px + rx;
                const int i00 = yi0[gy] * W_ + xi0[gx], i01 = yi0[gy] * W_ + xi1[gx];
                const int i10 = yi1[gy] * W_ + xi0[gx], i11 = yi1[gy] * W_ + xi1[gx];
                const float v0 = yw0[gy] * (xw0[gx] * srcc[i00] + xw1[gx] * srcc[i01])
                               + yw1[gy] * (xw0[gx] * srcc[i10] + xw1[gx] * srcc[i11]);
                const float v1 = yw0[gy] * (xw0[gx] * srcc[64 * HW_ + i00] + xw1[gx] * srcc[64 * HW_ + i01])
                               + yw1[gy] * (xw0[gx] * srcc[64 * HW_ + i10] + xw1[gx] * srcc[64 * HW_ + i11]);
                m0 = fmaxf(m0, v0);
                m1 = fmaxf(m1, v1);
            }
        }
        outtile[lane * NCELL + cell]        = m0;
        outtile[(lane + 64) * NCELL + cell] = m1;
    }
    __syncthreads();

    const vfloat4* lsrc = (const vfloat4*)outtile;
    vfloat4* dst = (vfloat4*)out + (size_t)n * (C_ * NCELL / 4) + cq * (CQ * NCELL / 4);
    for (int i = tid; i < CQ * NCELL / 4; i += 256) {
        __builtin_nontemporal_store(lsrc[i], &dst[i]);
    }
}

extern "C" void kernel_launch(void* const* d_in, const int* in_sizes, int n_in,
                              void* d_out, int out_size, void* d_ws, size_t ws_size,
                              hipStream_t stream) {
    const float* bottom = (const float*)d_in[0];   // (1, 512, 38, 50)
    const float* rois   = (const float*)d_in[1];   // (1024, 5)
    float* out = (float*)d_out;                    // (1024, 512, 7, 7)

    const size_t trans_bytes = (size_t)HW_ * C_ * sizeof(_Float16);
    if (ws_size >= trans_bytes) {
        _Float16* trans = (_Float16*)d_ws;
        dim3 tgrid((HW_ + 31) / 32, C_ / 32);
        transpose_kernel<<<tgrid, 256, 0, stream>>>(bottom, trans);
        croppool_kernel<<<NROIS * 4, 256, 0, stream>>>(trans, rois, out);
    } else {
        croppool_fallback<<<NROIS * 4, 256, 0, stream>>>(bottom, rois, out);
    }
}

// Round 11
// 46.146 us; speedup vs baseline: 1.4876x; 1.0090x over previous
//
#include <hip/hip_runtime.h>
#include <hip/hip_fp16.h>
#include <float.h>

#define C_    512
#define H_    38
#define W_    50
#define HW_   (H_ * W_)       // 1900
#define NROIS 1024
#define PS    7
#define PRE   14              // PS*2
#define NCELL 49              // PS*PS
#define CQ    128             // channels per block (quarter)
#define NGP   (PRE * PRE)     // 196 gridpoints

typedef float vfloat4 __attribute__((ext_vector_type(4)));
typedef _Float16 h2 __attribute__((ext_vector_type(2)));

__device__ inline h2 bch2(int v)       { return __builtin_bit_cast(h2, v); }
__device__ inline h2 bch2u(unsigned v) { return __builtin_bit_cast(h2, v); }
__device__ inline int bcint(h2 v)      { return __builtin_bit_cast(int, v); }

// ---------------------------------------------------------------------------
// Transpose + downconvert: bottom (C, H*W) f32 -> (H*W, C) fp16.
// ---------------------------------------------------------------------------
__global__ __launch_bounds__(256) void transpose_kernel(
    const float* __restrict__ in, _Float16* __restrict__ out) {
    __shared__ float tile[32][33];
    const int pix0 = blockIdx.x * 32;
    const int c0   = blockIdx.y * 32;
    const int tx = threadIdx.x & 31;
    const int ty = threadIdx.x >> 5;

    for (int i = ty; i < 32; i += 8) {
        int c = c0 + i, pix = pix0 + tx;
        tile[i][tx] = (pix < HW_) ? in[c * HW_ + pix] : 0.0f;
    }
    __syncthreads();
    for (int i = ty; i < 32; i += 8) {
        int pix = pix0 + i, c = c0 + tx;
        if (pix < HW_) out[pix * C_ + c] = (_Float16)tile[tx][i];
    }
}

// ---------------------------------------------------------------------------
// Main crop-and-maxpool kernel (transposed fp16 src: src[pix*512 + c]).
// grid = NROIS*4; block = 256 (4 waves). Block (n,cq): ROI n, channels
// [cq*128, cq*128+128).
// Wave's 4 x 16-lane groups own the cell's 4 gridpoints (q = lane>>4);
// lane loads 16B = 8 fp16 channels per corner. Cell loop unrolled x2 so
// 8 independent 1KB wave-loads are in flight (latency-bound fix).
// Max over gridpoints via shfl_xor(16)+shfl_xor(32). fp16 outtile [c][cell]
// (stride 49 halfwords -> conflict-free), 18.8 KB LDS -> 8 blocks/CU.
// ---------------------------------------------------------------------------
struct CellT {
    uint4 wv;
    uint4 v0, v1, v2, v3;
    int   cell;
};

__device__ __forceinline__ void cell_load(
    const _Float16* __restrict__ srcc, const int4* __restrict__ offt,
    const uint4* __restrict__ wgtt, int cell, int q, CellT& ci) {
    const int py = cell / PS, px = cell - PS * py;
    const int gp = (2 * py + (q >> 1)) * PRE + 2 * px + (q & 1);
    const int4 o = offt[gp];
    ci.wv = wgtt[gp];
    ci.cell = cell;
    ci.v0 = *(const uint4*)(srcc + o.x);
    ci.v1 = *(const uint4*)(srcc + o.y);
    ci.v2 = *(const uint4*)(srcc + o.z);
    ci.v3 = *(const uint4*)(srcc + o.w);
}

__device__ __forceinline__ void cell_math(
    const CellT& ci, int q, int m, _Float16* __restrict__ outtile) {
    const h2 w0 = bch2u(ci.wv.x), w1 = bch2u(ci.wv.y);
    const h2 w2 = bch2u(ci.wv.z), w3 = bch2u(ci.wv.w);

    h2 a0 = w0 * bch2u(ci.v0.x) + w1 * bch2u(ci.v1.x) + w2 * bch2u(ci.v2.x) + w3 * bch2u(ci.v3.x);
    h2 a1 = w0 * bch2u(ci.v0.y) + w1 * bch2u(ci.v1.y) + w2 * bch2u(ci.v2.y) + w3 * bch2u(ci.v3.y);
    h2 a2 = w0 * bch2u(ci.v0.z) + w1 * bch2u(ci.v1.z) + w2 * bch2u(ci.v2.z) + w3 * bch2u(ci.v3.z);
    h2 a3 = w0 * bch2u(ci.v0.w) + w1 * bch2u(ci.v1.w) + w2 * bch2u(ci.v2.w) + w3 * bch2u(ci.v3.w);

    #pragma unroll
    for (int s = 16; s <= 32; s <<= 1) {
        a0 = __builtin_elementwise_max(a0, bch2(__shfl_xor(bcint(a0), s, 64)));
        a1 = __builtin_elementwise_max(a1, bch2(__shfl_xor(bcint(a1), s, 64)));
        a2 = __builtin_elementwise_max(a2, bch2(__shfl_xor(bcint(a2), s, 64)));
        a3 = __builtin_elementwise_max(a3, bch2(__shfl_xor(bcint(a3), s, 64)));
    }

    const h2 sel = (q == 0) ? a0 : (q == 1) ? a1 : (q == 2) ? a2 : a3;
    const int c0 = 8 * m + 2 * q;
    outtile[c0 * NCELL + ci.cell]       = sel.x;
    outtile[(c0 + 1) * NCELL + ci.cell] = sel.y;
}

__global__ __launch_bounds__(256, 8) void croppool_kernel(
    const _Float16* __restrict__ src, const float* __restrict__ rois,
    float* __restrict__ out) {

    const int n  = blockIdx.x >> 2;
    const int cq = blockIdx.x & 3;
    const int cbase = cq * CQ;
    const int tid = threadIdx.x;

    __shared__ _Float16 outtile[CQ * NCELL];  // [c][cell], 12544 B
    __shared__ int4  offt[NGP];               // 4 corner offsets (half elems)
    __shared__ uint4 wgtt[NGP];               // 4 corner weights as packed h2

    // --- per-gridpoint tables (align_corners=True + zeros padding) ---
    if (tid < NGP) {
        const int gy = tid / PRE, gx = tid - PRE * gy;
        const float rx1 = rois[n * 5 + 1] * 0.0625f;
        const float ry1 = rois[n * 5 + 2] * 0.0625f;
        const float rx2 = rois[n * 5 + 3] * 0.0625f;
        const float ry2 = rois[n * 5 + 4] * 0.0625f;

        int xi0, xi1, yi0, yi1;
        float wx0, wx1, wy0, wy1;
        {   // x axis
            const float sz = (float)(W_ - 1);
            const float t0 = (rx2 - rx1) / sz, tc = (rx1 + rx2 - sz) / sz;
            const float base = -1.0f + (float)gx * (2.0f / 13.0f);
            const float coord = (t0 * base + tc + 1.0f) * 0.5f * sz;
            const float f = floorf(coord), a = coord - f;
            const int i0 = (int)f, i1 = i0 + 1;
            wx0 = (i0 >= 0 && i0 <= W_ - 1) ? (1.0f - a) : 0.0f;
            wx1 = (i1 >= 0 && i1 <= W_ - 1) ? a : 0.0f;
            xi0 = min(max(i0, 0), W_ - 1);
            xi1 = min(max(i1, 0), W_ - 1);
        }
        {   // y axis
            const float sz = (float)(H_ - 1);
            const float t0 = (ry2 - ry1) / sz, tc = (ry1 + ry2 - sz) / sz;
            const float base = -1.0f + (float)gy * (2.0f / 13.0f);
            const float coord = (t0 * base + tc + 1.0f) * 0.5f * sz;
            const float f = floorf(coord), a = coord - f;
            const int i0 = (int)f, i1 = i0 + 1;
            wy0 = (i0 >= 0 && i0 <= H_ - 1) ? (1.0f - a) : 0.0f;
            wy1 = (i1 >= 0 && i1 <= H_ - 1) ? a : 0.0f;
            yi0 = min(max(i0, 0), H_ - 1);
            yi1 = min(max(i1, 0), H_ - 1);
        }
        offt[tid] = make_int4((yi0 * W_ + xi0) * C_, (yi0 * W_ + xi1) * C_,
                              (yi1 * W_ + xi0) * C_, (yi1 * W_ + xi1) * C_);
        const _Float16 w0 = (_Float16)(wy0 * wx0);
        const _Float16 w1 = (_Float16)(wy0 * wx1);
        const _Float16 w2 = (_Float16)(wy1 * wx0);
        const _Float16 w3 = (_Float16)(wy1 * wx1);
        uint4 wv;
        wv.x = __builtin_bit_cast(unsigned, (h2){w0, w0});
        wv.y = __builtin_bit_cast(unsigned, (h2){w1, w1});
        wv.z = __builtin_bit_cast(unsigned, (h2){w2, w2});
        wv.w = __builtin_bit_cast(unsigned, (h2){w3, w3});
        wgtt[tid] = wv;
    }
    __syncthreads();

    const int m    = tid & 15;          // channel octet (8 ch each)
    const int q    = (tid >> 4) & 3;    // gridpoint quarter of the cell
    const int wave = tid >> 6;
    const _Float16* srcc = src + cbase + 8 * m;

    // --- 2x-unrolled cell loop: 8 independent wave-loads in flight ---
    int cell = wave;
    for (; cell + 4 < NCELL; cell += 8) {
        CellT c0i, c1i;
        cell_load(srcc, offt, wgtt, cell,     q, c0i);
        cell_load(srcc, offt, wgtt, cell + 4, q, c1i);
        cell_math(c0i, q, m, outtile);
        cell_math(c1i, q, m, outtile);
    }
    if (cell < NCELL) {
        CellT ci;
        cell_load(srcc, offt, wgtt, cell, q, ci);
        cell_math(ci, q, m, outtile);
    }
    __syncthreads();

    // --- flush: contiguous b128 LDS reads, fp16->f32, contiguous nt stores ---
    float* dstb = out + (size_t)n * (C_ * NCELL) + cbase * NCELL;
    const uint4* lsrc = (const uint4*)outtile;
    for (int g = tid; g < CQ * NCELL / 8; g += 256) {
        const uint4 p = lsrc[g];
        vfloat4 lo, hi;
        h2 h;
        h = bch2u(p.x); lo[0] = (float)h.x; lo[1] = (float)h.y;
        h = bch2u(p.y); lo[2] = (float)h.x; lo[3] = (float)h.y;
        h = bch2u(p.z); hi[0] = (float)h.x; hi[1] = (float)h.y;
        h = bch2u(p.w); hi[2] = (float)h.x; hi[3] = (float)h.y;
        __builtin_nontemporal_store(lo, (vfloat4*)(dstb + 8 * g));
        __builtin_nontemporal_store(hi, (vfloat4*)(dstb + 8 * g + 4));
    }
}

// ---------------------------------------------------------------------------
// Fallback (reads original (C,H*W) f32 layout directly) — only if d_ws tiny.
// ---------------------------------------------------------------------------
__global__ __launch_bounds__(256) void croppool_fallback(
    const float* __restrict__ src, const float* __restrict__ rois,
    float* __restrict__ out) {

    const int n  = blockIdx.x >> 2;
    const int cq = blockIdx.x & 3;
    const int cbase = cq * CQ;
    const int tid = threadIdx.x;

    __shared__ float outtile[CQ * NCELL];
    __shared__ int   xi0[PRE], xi1[PRE], yi0[PRE], yi1[PRE];
    __shared__ float xw0[PRE], xw1[PRE], yw0[PRE], yw1[PRE];

    if (tid < 2 * PRE) {
        const int  j   = tid % PRE;
        const bool isy = tid >= PRE;
        const float r1 = rois[n * 5 + (isy ? 2 : 1)] * 0.0625f;
        const float r2 = rois[n * 5 + (isy ? 4 : 3)] * 0.0625f;
        const float sz = isy ? (float)(H_ - 1) : (float)(W_ - 1);
        const int  szi = isy ? (H_ - 1) : (W_ - 1);
        const float t0 = (r2 - r1) / sz;
        const float tc = (r1 + r2 - sz) / sz;
        const float base = -1.0f + (float)j * (2.0f / 13.0f);
        const float coord = (t0 * base + tc + 1.0f) * 0.5f * sz;
        const float f = floorf(coord);
        const float a = coord - f;
        const int i0 = (int)f;
        const int i1 = i0 + 1;
        const float w0 = (i0 >= 0 && i0 <= szi) ? (1.0f - a) : 0.0f;
        const float w1 = (i1 >= 0 && i1 <= szi) ? a : 0.0f;
        const int i0c = min(max(i0, 0), szi);
        const int i1c = min(max(i1, 0), szi);
        if (isy) { yi0[j] = i0c; yi1[j] = i1c; yw0[j] = w0; yw1[j] = w1; }
        else     { xi0[j] = i0c; xi1[j] = i1c; xw0[j] = w0; xw1[j] = w1; }
    }
    __syncthreads();

    const int wave = tid >> 6;
    const int lane = tid & 63;
    const float* srcc = src + (size_t)(cbase + lane) * HW_;

    for (int cell = wave; cell < NCELL; cell += 4) {
        const int py = cell / PS, px = cell % PS;
        float m0 = -FLT_MAX, m1 = -FLT_MAX;
        for (int ry = 0; ry < 2; ++ry) {
            const int gy = 2 * py + ry;
            for (int rx = 0; rx < 2; ++rx) {
                const int gx = 2 * px + rx;
                const int i00 = yi0[gy] * W_ + xi0[gx], i01 = yi0[gy] * W_ + xi1[gx];
                const int i10 = yi1[gy] * W_ + xi0[gx], i11 = yi1[gy] * W_ + xi1[gx];
                const float v0 = yw0[gy] * (xw0[gx] * srcc[i00] + xw1[gx] * srcc[i01])
                               + yw1[gy] * (xw0[gx] * srcc[i10] + xw1[gx] * srcc[i11]);
                const float v1 = yw0[gy] * (xw0[gx] * srcc[64 * HW_ + i00] + xw1[gx] * srcc[64 * HW_ + i01])
                               + yw1[gy] * (xw0[gx] * srcc[64 * HW_ + i10] + xw1[gx] * srcc[64 * HW_ + i11]);
                m0 = fmaxf(m0, v0);
                m1 = fmaxf(m1, v1);
            }
        }
        outtile[lane * NCELL + cell]        = m0;
        outtile[(lane + 64) * NCELL + cell] = m1;
    }
    __syncthreads();

    const vfloat4* lsrc = (const vfloat4*)outtile;
    vfloat4* dst = (vfloat4*)out + (size_t)n * (C_ * NCELL / 4) + cq * (CQ * NCELL / 4);
    for (int i = tid; i < CQ * NCELL / 4; i += 256) {
        __builtin_nontemporal_store(lsrc[i], &dst[i]);
    }
}

extern "C" void kernel_launch(void* const* d_in, const int* in_sizes, int n_in,
                              void* d_out, int out_size, void* d_ws, size_t ws_size,
                              hipStream_t stream) {
    const float* bottom = (const float*)d_in[0];   // (1, 512, 38, 50)
    const float* rois   = (const float*)d_in[1];   // (1024, 5)
    float* out = (float*)d_out;                    // (1024, 512, 7, 7)

    const size_t trans_bytes = (size_t)HW_ * C_ * sizeof(_Float16);
    if (ws_size >= trans_bytes) {
        _Float16* trans = (_Float16*)d_ws;
        dim3 tgrid((HW_ + 31) / 32, C_ / 32);
        transpose_kernel<<<tgrid, 256, 0, stream>>>(bottom, trans);
        croppool_kernel<<<NROIS * 4, 256, 0, stream>>>(trans, rois, out);
    } else {
        croppool_fallback<<<NROIS * 4, 256, 0, stream>>>(bottom, rois, out);
    }
}

// Round 12
// 43.093 us; speedup vs baseline: 1.5930x; 1.0708x over previous
//
#include <hip/hip_runtime.h>
#include <hip/hip_fp16.h>
#include <float.h>

#define C_    512
#define H_    38
#define W_    50
#define HW_   (H_ * W_)       // 1900
#define NROIS 1024
#define PS    7
#define PRE   14              // PS*2
#define NCELL 49              // PS*PS
#define NGP   (PRE * PRE)     // 196 gridpoints
#define OTP   516             // outtile row stride (halfwords): 8B-aligned rows,
                              // bank stride 258%32=2 -> ~2-4-way on flush reads only

typedef float vfloat4 __attribute__((ext_vector_type(4)));
typedef _Float16 h2 __attribute__((ext_vector_type(2)));

__device__ inline h2 bch2u(unsigned v)   { return __builtin_bit_cast(h2, v); }
__device__ inline unsigned bcu(h2 v)     { return __builtin_bit_cast(unsigned, v); }

// ---------------------------------------------------------------------------
// Transpose + downconvert: bottom (C, H*W) f32 -> (H*W, C) fp16.
// ---------------------------------------------------------------------------
__global__ __launch_bounds__(256) void transpose_kernel(
    const float* __restrict__ in, _Float16* __restrict__ out) {
    __shared__ float tile[32][33];
    const int pix0 = blockIdx.x * 32;
    const int c0   = blockIdx.y * 32;
    const int tx = threadIdx.x & 31;
    const int ty = threadIdx.x >> 5;

    for (int i = ty; i < 32; i += 8) {
        int c = c0 + i, pix = pix0 + tx;
        tile[i][tx] = (pix < HW_) ? in[c * HW_ + pix] : 0.0f;
    }
    __syncthreads();
    for (int i = ty; i < 32; i += 8) {
        int pix = pix0 + i, c = c0 + tx;
        if (pix < HW_) out[pix * C_ + c] = (_Float16)tile[tx][i];
    }
}

// ---------------------------------------------------------------------------
// Main crop-and-maxpool kernel (transposed fp16 src: src[pix*512 + c]).
// grid = NROIS; block = 512 (8 waves), one ROI per block.
// A wave covers ALL 512 channels (lane owns 8 ch = 16B). Corner load =
// src[pix*512 + 8*lane] -> ONE contiguous aligned 1KB single-segment
// wave-load. Per cell: 16 independent corner loads, bilinear FMA + 3
// packed maxes, all per-lane — NO cross-lane ops. fp16 outtile
// [cell][c] (stride 516) -> conflict-free ds_write_b64; flush scalar.
// LDS 56.8 KB -> 2 blocks/CU (16 waves/CU).
// ---------------------------------------------------------------------------
__global__ __launch_bounds__(512, 4) void croppool_kernel(
    const _Float16* __restrict__ src, const float* __restrict__ rois,
    float* __restrict__ out) {

    const int n   = blockIdx.x;
    const int tid = threadIdx.x;

    __shared__ _Float16 outtile[NCELL * OTP];   // 50568 B
    __shared__ int4  offt[NGP];                 // 4 corner offsets (elems)
    __shared__ uint4 wgtt[NGP];                 // 4 corner weights as packed h2

    // --- per-gridpoint tables (align_corners=True + zeros padding) ---
    if (tid < NGP) {
        const int gy = tid / PRE, gx = tid - PRE * gy;
        const float rx1 = rois[n * 5 + 1] * 0.0625f;
        const float ry1 = rois[n * 5 + 2] * 0.0625f;
        const float rx2 = rois[n * 5 + 3] * 0.0625f;
        const float ry2 = rois[n * 5 + 4] * 0.0625f;

        int xi0, xi1, yi0, yi1;
        float wx0, wx1, wy0, wy1;
        {   // x axis
            const float sz = (float)(W_ - 1);
            const float t0 = (rx2 - rx1) / sz, tc = (rx1 + rx2 - sz) / sz;
            const float base = -1.0f + (float)gx * (2.0f / 13.0f);
            const float coord = (t0 * base + tc + 1.0f) * 0.5f * sz;
            const float f = floorf(coord), a = coord - f;
            const int i0 = (int)f, i1 = i0 + 1;
            wx0 = (i0 >= 0 && i0 <= W_ - 1) ? (1.0f - a) : 0.0f;
            wx1 = (i1 >= 0 && i1 <= W_ - 1) ? a : 0.0f;
            xi0 = min(max(i0, 0), W_ - 1);
            xi1 = min(max(i1, 0), W_ - 1);
        }
        {   // y axis
            const float sz = (float)(H_ - 1);
            const float t0 = (ry2 - ry1) / sz, tc = (ry1 + ry2 - sz) / sz;
            const float base = -1.0f + (float)gy * (2.0f / 13.0f);
            const float coord = (t0 * base + tc + 1.0f) * 0.5f * sz;
            const float f = floorf(coord), a = coord - f;
            const int i0 = (int)f, i1 = i0 + 1;
            wy0 = (i0 >= 0 && i0 <= H_ - 1) ? (1.0f - a) : 0.0f;
            wy1 = (i1 >= 0 && i1 <= H_ - 1) ? a : 0.0f;
            yi0 = min(max(i0, 0), H_ - 1);
            yi1 = min(max(i1, 0), H_ - 1);
        }
        offt[tid] = make_int4((yi0 * W_ + xi0) * C_, (yi0 * W_ + xi1) * C_,
                              (yi1 * W_ + xi0) * C_, (yi1 * W_ + xi1) * C_);
        const _Float16 w0 = (_Float16)(wy0 * wx0);
        const _Float16 w1 = (_Float16)(wy0 * wx1);
        const _Float16 w2 = (_Float16)(wy1 * wx0);
        const _Float16 w3 = (_Float16)(wy1 * wx1);
        uint4 wv;
        wv.x = bcu((h2){w0, w0});
        wv.y = bcu((h2){w1, w1});
        wv.z = bcu((h2){w2, w2});
        wv.w = bcu((h2){w3, w3});
        wgtt[tid] = wv;
    }
    __syncthreads();

    const int lane = tid & 63;
    const int wave = tid >> 6;                 // 0..7
    const _Float16* srcc = src + 8 * lane;     // lane's 8 channels

    for (int cell = wave; cell < NCELL; cell += 8) {
        const int py = cell / PS, px = cell - PS * py;
        const int gb = 2 * py * PRE + 2 * px;
        const int gps0 = gb, gps1 = gb + 1, gps2 = gb + PRE, gps3 = gb + PRE + 1;

        // issue all 16 corner loads (single-segment 1KB wave-loads)
        uint4 WV0 = wgtt[gps0], WV1 = wgtt[gps1], WV2 = wgtt[gps2], WV3 = wgtt[gps3];
        const int4 o0 = offt[gps0], o1 = offt[gps1], o2 = offt[gps2], o3 = offt[gps3];
        const uint4 V00 = *(const uint4*)(srcc + o0.x);
        const uint4 V01 = *(const uint4*)(srcc + o0.y);
        const uint4 V02 = *(const uint4*)(srcc + o0.z);
        const uint4 V03 = *(const uint4*)(srcc + o0.w);
        const uint4 V10 = *(const uint4*)(srcc + o1.x);
        const uint4 V11 = *(const uint4*)(srcc + o1.y);
        const uint4 V12 = *(const uint4*)(srcc + o1.z);
        const uint4 V13 = *(const uint4*)(srcc + o1.w);
        const uint4 V20 = *(const uint4*)(srcc + o2.x);
        const uint4 V21 = *(const uint4*)(srcc + o2.y);
        const uint4 V22 = *(const uint4*)(srcc + o2.z);
        const uint4 V23 = *(const uint4*)(srcc + o2.w);
        const uint4 V30 = *(const uint4*)(srcc + o3.x);
        const uint4 V31 = *(const uint4*)(srcc + o3.y);
        const uint4 V32 = *(const uint4*)(srcc + o3.z);
        const uint4 V33 = *(const uint4*)(srcc + o3.w);

        h2 m0, m1, m2, m3;
        {
            const h2 w0 = bch2u(WV0.x), w1 = bch2u(WV0.y), w2 = bch2u(WV0.z), w3 = bch2u(WV0.w);
            m0 = w0 * bch2u(V00.x) + w1 * bch2u(V01.x) + w2 * bch2u(V02.x) + w3 * bch2u(V03.x);
            m1 = w0 * bch2u(V00.y) + w1 * bch2u(V01.y) + w2 * bch2u(V02.y) + w3 * bch2u(V03.y);
            m2 = w0 * bch2u(V00.z) + w1 * bch2u(V01.z) + w2 * bch2u(V02.z) + w3 * bch2u(V03.z);
            m3 = w0 * bch2u(V00.w) + w1 * bch2u(V01.w) + w2 * bch2u(V02.w) + w3 * bch2u(V03.w);
        }
        {
            const h2 w0 = bch2u(WV1.x), w1 = bch2u(WV1.y), w2 = bch2u(WV1.z), w3 = bch2u(WV1.w);
            const h2 a0 = w0 * bch2u(V10.x) + w1 * bch2u(V11.x) + w2 * bch2u(V12.x) + w3 * bch2u(V13.x);
            const h2 a1 = w0 * bch2u(V10.y) + w1 * bch2u(V11.y) + w2 * bch2u(V12.y) + w3 * bch2u(V13.y);
            const h2 a2 = w0 * bch2u(V10.z) + w1 * bch2u(V11.z) + w2 * bch2u(V12.z) + w3 * bch2u(V13.z);
            const h2 a3 = w0 * bch2u(V10.w) + w1 * bch2u(V11.w) + w2 * bch2u(V12.w) + w3 * bch2u(V13.w);
            m0 = __builtin_elementwise_max(m0, a0);
            m1 = __builtin_elementwise_max(m1, a1);
            m2 = __builtin_elementwise_max(m2, a2);
            m3 = __builtin_elementwise_max(m3, a3);
        }
        {
            const h2 w0 = bch2u(WV2.x), w1 = bch2u(WV2.y), w2 = bch2u(WV2.z), w3 = bch2u(WV2.w);
            const h2 a0 = w0 * bch2u(V20.x) + w1 * bch2u(V21.x) + w2 * bch2u(V22.x) + w3 * bch2u(V23.x);
            const h2 a1 = w0 * bch2u(V20.y) + w1 * bch2u(V21.y) + w2 * bch2u(V22.y) + w3 * bch2u(V23.y);
            const h2 a2 = w0 * bch2u(V20.z) + w1 * bch2u(V21.z) + w2 * bch2u(V22.z) + w3 * bch2u(V23.z);
            const h2 a3 = w0 * bch2u(V20.w) + w1 * bch2u(V21.w) + w2 * bch2u(V22.w) + w3 * bch2u(V23.w);
            m0 = __builtin_elementwise_max(m0, a0);
            m1 = __builtin_elementwise_max(m1, a1);
            m2 = __builtin_elementwise_max(m2, a2);
            m3 = __builtin_elementwise_max(m3, a3);
        }
        {
            const h2 w0 = bch2u(WV3.x), w1 = bch2u(WV3.y), w2 = bch2u(WV3.z), w3 = bch2u(WV3.w);
            const h2 a0 = w0 * bch2u(V30.x) + w1 * bch2u(V31.x) + w2 * bch2u(V32.x) + w3 * bch2u(V33.x);
            const h2 a1 = w0 * bch2u(V30.y) + w1 * bch2u(V31.y) + w2 * bch2u(V32.y) + w3 * bch2u(V33.y);
            const h2 a2 = w0 * bch2u(V30.z) + w1 * bch2u(V31.z) + w2 * bch2u(V32.z) + w3 * bch2u(V33.z);
            const h2 a3 = w0 * bch2u(V30.w) + w1 * bch2u(V31.w) + w2 * bch2u(V32.w) + w3 * bch2u(V33.w);
            m0 = __builtin_elementwise_max(m0, a0);
            m1 = __builtin_elementwise_max(m1, a1);
            m2 = __builtin_elementwise_max(m2, a2);
            m3 = __builtin_elementwise_max(m3, a3);
        }

        // lane writes its 8 channels: two 8B-aligned ds_write_b64 (conflict-free)
        _Float16* dst = &outtile[cell * OTP + 8 * lane];
        uint2 lo, hi;
        lo.x = bcu(m0); lo.y = bcu(m1);
        hi.x = bcu(m2); hi.y = bcu(m3);
        *(uint2*)dst       = lo;
        *(uint2*)(dst + 4) = hi;
    }
    __syncthreads();

    // --- flush: transpose [cell][c] -> out[n][c][cell], coalesced dword stores ---
    float* dstb = out + (size_t)n * (C_ * NCELL);
    for (int f = tid; f < C_ * NCELL; f += 512) {
        const int c = f / NCELL, cell = f - NCELL * c;
        __builtin_nontemporal_store((float)outtile[cell * OTP + c], &dstb[f]);
    }
}

// ---------------------------------------------------------------------------
// Fallback (reads original (C,H*W) f32 layout directly) — only if d_ws tiny.
// ---------------------------------------------------------------------------
__global__ __launch_bounds__(256) void croppool_fallback(
    const float* __restrict__ src, const float* __restrict__ rois,
    float* __restrict__ out) {

    const int n  = blockIdx.x >> 2;
    const int cq = blockIdx.x & 3;
    const int cbase = cq * 128;
    const int tid = threadIdx.x;

    __shared__ float outtile[128 * NCELL];
    __shared__ int   xi0[PRE], xi1[PRE], yi0[PRE], yi1[PRE];
    __shared__ float xw0[PRE], xw1[PRE], yw0[PRE], yw1[PRE];

    if (tid < 2 * PRE) {
        const int  j   = tid % PRE;
        const bool isy = tid >= PRE;
        const float r1 = rois[n * 5 + (isy ? 2 : 1)] * 0.0625f;
        const float r2 = rois[n * 5 + (isy ? 4 : 3)] * 0.0625f;
        const float sz = isy ? (float)(H_ - 1) : (float)(W_ - 1);
        const int  szi = isy ? (H_ - 1) : (W_ - 1);
        const float t0 = (r2 - r1) / sz;
        const float tc = (r1 + r2 - sz) / sz;
        const float base = -1.0f + (float)j * (2.0f / 13.0f);
        const float coord = (t0 * base + tc + 1.0f) * 0.5f * sz;
        const float f = floorf(coord);
        const float a = coord - f;
        const int i0 = (int)f;
        const int i1 = i0 + 1;
        const float w0 = (i0 >= 0 && i0 <= szi) ? (1.0f - a) : 0.0f;
        const float w1 = (i1 >= 0 && i1 <= szi) ? a : 0.0f;
        const int i0c = min(max(i0, 0), szi);
        const int i1c = min(max(i1, 0), szi);
        if (isy) { yi0[j] = i0c; yi1[j] = i1c; yw0[j] = w0; yw1[j] = w1; }
        else     { xi0[j] = i0c; xi1[j] = i1c; xw0[j] = w0; xw1[j] = w1; }
    }
    __syncthreads();

    const int wave = tid >> 6;
    const int lane = tid & 63;
    const float* srcc = src + (size_t)(cbase + lane) * HW_;

    for (int cell = wave; cell < NCELL; cell += 4) {
        const int py = cell / PS, px = cell % PS;
        float m0 = -FLT_MAX, m1 = -FLT_MAX;
        for (int ry = 0; ry < 2; ++ry) {
            const int gy = 2 * py + ry;
            for (int rx = 0; rx < 2; ++rx) {
                const int gx = 2 * px + rx;
                const int i00 = yi0[gy] * W_ + xi0[gx], i01 = yi0[gy] * W_ + xi1[gx];
                const int i10 = yi1[gy] * W_ + xi0[gx], i11 = yi1[gy] * W_ + xi1[gx];
                const float v0 = yw0[gy] * (xw0[gx] * srcc[i00] + xw1[gx] * srcc[i01])
                               + yw1[gy] * (xw0[gx] * srcc[i10] + xw1[gx] * srcc[i11]);
                const float v1 = yw0[gy] * (xw0[gx] * srcc[64 * HW_ + i00] + xw1[gx] * srcc[64 * HW_ + i01])
                               + yw1[gy] * (xw0[gx] * srcc[64 * HW_ + i10] + xw1[gx] * srcc[64 * HW_ + i11]);
                m0 = fmaxf(m0, v0);
                m1 = fmaxf(m1, v1);
            }
        }
        outtile[lane * NCELL + cell]        = m0;
        outtile[(lane + 64) * NCELL + cell] = m1;
    }
    __syncthreads();

    const vfloat4* lsrc = (const vfloat4*)outtile;
    vfloat4* dst = (vfloat4*)out + (size_t)n * (C_ * NCELL / 4) + cq * (128 * NCELL / 4);
    for (int i = tid; i < 128 * NCELL / 4; i += 256) {
        __builtin_nontemporal_store(lsrc[i], &dst[i]);
    }
}

extern "C" void kernel_launch(void* const* d_in, const int* in_sizes, int n_in,
                              void* d_out, int out_size, void* d_ws, size_t ws_size,
                              hipStream_t stream) {
    const float* bottom = (const float*)d_in[0];   // (1, 512, 38, 50)
    const float* rois   = (const float*)d_in[1];   // (1024, 5)
    float* out = (float*)d_out;                    // (1024, 512, 7, 7)

    const size_t trans_bytes = (size_t)HW_ * C_ * sizeof(_Float16);
    if (ws_size >= trans_bytes) {
        _Float16* trans = (_Float16*)d_ws;
        dim3 tgrid((HW_ + 31) / 32, C_ / 32);
        transpose_kernel<<<tgrid, 256, 0, stream>>>(bottom, trans);
        croppool_kernel<<<NROIS, 512, 0, stream>>>(trans, rois, out);
    } else {
        croppool_fallback<<<NROIS * 4, 256, 0, stream>>>(bottom, rois, out);
    }
}